// Round 1
// baseline (3435.460 us; speedup 1.0000x reference)
//
#include <hip/hip_runtime.h>

// Problem constants (fixed by the reference)
#define NN 8192
#define HH 200
#define EE 524288

constexpr int BM = 64, BN = 64, BK = 16;

// C[M,N] = A[M,K] @ B[K,N], where B is the column-concat of three [K,200]
// row-major matrices B0|B1|B2. Works for N=600 (3 segments) and N=200 (B0 only,
// pass the same pointer thrice). 64x64 tile, 4x4 per thread, 256 threads.
__global__ __launch_bounds__(256) void gemm3_f32(
    const float* __restrict__ A,
    const float* __restrict__ B0, const float* __restrict__ B1,
    const float* __restrict__ B2,
    float* __restrict__ C, int M, int N, int K)
{
    __shared__ float As[BK][BM];   // [k][m]
    __shared__ float Bs[BK][BN];   // [k][n]

    const int tid  = threadIdx.x;
    const int row0 = blockIdx.y * BM;
    const int col0 = blockIdx.x * BN;

    // A-tile load mapping: 64 rows x 16 k, float4 per thread
    const int a_r = tid >> 2;           // 0..63
    const int a_c = (tid & 3) << 2;     // 0,4,8,12
    // B-tile load mapping: 16 k x 64 cols, float4 per thread
    const int b_r = tid >> 4;           // 0..15
    const int b_c = (tid & 15) << 2;    // 0..60

    const int gcol = col0 + b_c;        // global B column for this thread
    const bool bvalid = (gcol < N);     // N%4==0 and gcol%4==0 -> whole float4 valid
    int seg = gcol / 200; if (seg > 2) seg = 2;
    const float* Bp = (seg == 0) ? B0 : ((seg == 1) ? B1 : B2);
    const int bcc = gcol - seg * 200;   // column within the segment

    // compute micro-tile position
    const int m0 = (tid >> 4) << 2;     // 0..60
    const int n0 = (tid & 15) << 2;     // 0..60

    float acc[4][4];
#pragma unroll
    for (int i = 0; i < 4; i++)
#pragma unroll
        for (int j = 0; j < 4; j++) acc[i][j] = 0.f;

    for (int k0 = 0; k0 < K; k0 += BK) {
        // ---- stage A tile (transpose into As[k][m]) ----
        float4 av = make_float4(0.f, 0.f, 0.f, 0.f);
        const int ak = k0 + a_c;
        if (ak < K)   // K%4==0, ak%4==0 -> whole float4 in-bounds iff ak<K
            av = *(const float4*)(A + (size_t)(row0 + a_r) * K + ak);
        As[a_c + 0][a_r] = av.x;
        As[a_c + 1][a_r] = av.y;
        As[a_c + 2][a_r] = av.z;
        As[a_c + 3][a_r] = av.w;

        // ---- stage B tile ----
        float4 bv = make_float4(0.f, 0.f, 0.f, 0.f);
        const int bk = k0 + b_r;
        if (bvalid && bk < K)
            bv = *(const float4*)(Bp + (size_t)bk * 200 + bcc);
        *(float4*)&Bs[b_r][b_c] = bv;

        __syncthreads();

#pragma unroll
        for (int k = 0; k < BK; k++) {
            float4 a4 = *(const float4*)&As[k][m0];
            float4 b4 = *(const float4*)&Bs[k][n0];
            float ar[4] = {a4.x, a4.y, a4.z, a4.w};
            float br[4] = {b4.x, b4.y, b4.z, b4.w};
#pragma unroll
            for (int i = 0; i < 4; i++)
#pragma unroll
                for (int j = 0; j < 4; j++)
                    acc[i][j] = fmaf(ar[i], br[j], acc[i][j]);
        }
        __syncthreads();
    }

#pragma unroll
    for (int i = 0; i < 4; i++) {
        const int r = row0 + m0 + i;   // always < M (M multiple of 64)
#pragma unroll
        for (int j = 0; j < 4; j++) {
            const int c = col0 + n0 + j;
            if (c < N) C[(size_t)r * N + c] = acc[i][j];
        }
    }
}

// h[n,j] = y[n, j] (self columns of the 600-wide buffer) + b[j]
__global__ void init_h_kernel(const float* __restrict__ y,
                              const float* __restrict__ b,
                              float* __restrict__ h)
{
    int i = blockIdx.x * 256 + threadIdx.x;
    if (i >= NN * HH) return;
    int n = i / HH, j = i - n * HH;
    h[i] = y[(size_t)n * 600 + j] + b[j];
}

// h[dst] += y[src, yoff : yoff+200];  one block (256 thr, 200 active) per edge
__global__ void scatter_add_kernel(const float* __restrict__ y, int yoff,
                                   const int* __restrict__ edges,
                                   float* __restrict__ h)
{
    int e = blockIdx.x;
    int j = threadIdx.x;
    if (j >= HH) return;
    int src = edges[e];
    int dst = edges[EE + e];
    atomicAdd(&h[(size_t)dst * HH + j], y[(size_t)src * 600 + yoff + j]);
}

__global__ void relu_kernel(float* __restrict__ h, int n)
{
    int i = blockIdx.x * 256 + threadIdx.x;
    if (i < n) h[i] = fmaxf(h[i], 0.f);
}

// pred[e] = mask[e] ? dot(hQ[src], h2[dst]) + 3.5 : 0 ; one wave per edge
__global__ void pred_kernel(const float* __restrict__ hQ,
                            const float* __restrict__ h2,
                            const int* __restrict__ edge_rat,
                            const int* __restrict__ mask,
                            float* __restrict__ out)
{
    int gid  = blockIdx.x * blockDim.x + threadIdx.x;
    int e    = gid >> 6;
    int lane = gid & 63;
    if (e >= EE) return;
    int src = edge_rat[e];
    int dst = edge_rat[EE + e];
    const float* a = hQ + (size_t)src * HH;
    const float* b = h2 + (size_t)dst * HH;
    float s = 0.f;
    for (int j = lane; j < HH; j += 64) s = fmaf(a[j], b[j], s);
#pragma unroll
    for (int off = 32; off > 0; off >>= 1) s += __shfl_down(s, off, 64);
    if (lane == 0) out[e] = mask[e] ? (s + 3.5f) : 0.f;
}

extern "C" void kernel_launch(void* const* d_in, const int* in_sizes, int n_in,
                              void* d_out, int out_size, void* d_ws, size_t ws_size,
                              hipStream_t stream)
{
    const float* x       = (const float*)d_in[0];
    const int*   e_sim   = (const int*)d_in[1];
    const int*   e_rat   = (const int*)d_in[2];
    const int*   mask    = (const int*)d_in[3];
    const float* w1_self = (const float*)d_in[4];
    const float* w1_sim  = (const float*)d_in[5];
    const float* w1_rat  = (const float*)d_in[6];
    const float* b1      = (const float*)d_in[7];
    const float* w2_self = (const float*)d_in[8];
    const float* w2_sim  = (const float*)d_in[9];
    const float* w2_rat  = (const float*)d_in[10];
    const float* b2      = (const float*)d_in[11];
    const float* Q       = (const float*)d_in[12];
    float* out = (float*)d_out;

    char* ws = (char*)d_ws;
    float* y  = (float*)ws;                                   // [8192,600] 19.66 MB
    float* h1 = (float*)(ws + (size_t)NN * 600 * 4);          // [8192,200]  6.55 MB
    float* h2 = (float*)(ws + (size_t)NN * 600 * 4 + (size_t)NN * HH * 4);
    float* hQ = y;  // reuse y region once y2 is consumed

    const dim3 blk(256);
    const dim3 g_gemm600((600 + BN - 1) / BN, NN / BM);
    const dim3 g_gemm200((HH + BN - 1) / BN, NN / BM);
    const int  g_nh = (NN * HH + 255) / 256;

    // ---- layer 1 ----
    gemm3_f32<<<g_gemm600, blk, 0, stream>>>(x, w1_self, w1_sim, w1_rat, y,
                                             NN, 600, NN);
    init_h_kernel<<<g_nh, blk, 0, stream>>>(y, b1, h1);
    scatter_add_kernel<<<EE, blk, 0, stream>>>(y, 200, e_sim, h1);
    scatter_add_kernel<<<EE, blk, 0, stream>>>(y, 400, e_rat, h1);
    relu_kernel<<<g_nh, blk, 0, stream>>>(h1, NN * HH);

    // ---- layer 2 ----
    gemm3_f32<<<g_gemm600, blk, 0, stream>>>(h1, w2_self, w2_sim, w2_rat, y,
                                             NN, 600, HH);
    init_h_kernel<<<g_nh, blk, 0, stream>>>(y, b2, h2);
    scatter_add_kernel<<<EE, blk, 0, stream>>>(y, 200, e_sim, h2);
    scatter_add_kernel<<<EE, blk, 0, stream>>>(y, 400, e_rat, h2);

    // ---- decoder ----
    gemm3_f32<<<g_gemm200, blk, 0, stream>>>(h2, Q, Q, Q, hQ, NN, HH, HH);
    pred_kernel<<<(EE * 64) / 256, blk, 0, stream>>>(hQ, h2, e_rat, mask, out);
}

// Round 2
// 1243.787 us; speedup vs baseline: 2.7621x; 2.7621x over previous
//
#include <hip/hip_runtime.h>

#define NN 8192
#define EE 524288
#define HPAD 256   // hidden 200 padded to 256 (K padding for MFMA gemms)
#define NP 640     // 3*200 output cols padded to 640 (5 x 128 tiles)

using s16x8 = __attribute__((ext_vector_type(8))) short;
using f32x4 = __attribute__((ext_vector_type(4))) float;

__device__ __forceinline__ unsigned short f2b(float f) {
    unsigned u = __float_as_uint(f);
    u = (u + 0x7FFFu + ((u >> 16) & 1u)) >> 16;   // round-to-nearest-even
    return (unsigned short)u;
}

// ---------------- conversions ----------------

__global__ void cvt_x_kernel(const float* __restrict__ x,
                             unsigned short* __restrict__ xb)
{
    size_t i = (size_t)blockIdx.x * 256 + threadIdx.x;   // one float4 per thread
    float4 v = ((const float4*)x)[i];
    ushort4 o;
    o.x = f2b(v.x); o.y = f2b(v.y); o.z = f2b(v.z); o.w = f2b(v.w);
    ((ushort4*)xb)[i] = o;
}

// h [8192,200] f32 -> hb [8192,HPAD] bf16, zero-padded cols 200..255
__global__ void cvt_h_kernel(const float* __restrict__ h,
                             unsigned short* __restrict__ hb)
{
    int i = blockIdx.x * 256 + threadIdx.x;      // i in [0, 8192*64)
    int n = i >> 6, j4 = (i & 63) << 2;
    ushort4 o = {0, 0, 0, 0};
    if (j4 < 200) {
        const float* p = h + (size_t)n * 200 + j4;
        o.x = f2b(p[0]); o.y = f2b(p[1]); o.z = f2b(p[2]); o.w = f2b(p[3]);
    }
    ((ushort4*)hb)[i] = o;
}

// out[n][k] (bf16, [Nout=grid.y*32, Kout]) = concat(w0|w1|w2)[k][n], zero-padded.
// Source matrices are [Kreal, 200] f32 row-major (ld = 200).
__global__ void transpose_w_kernel(const float* __restrict__ w0,
                                   const float* __restrict__ w1,
                                   const float* __restrict__ w2,
                                   unsigned short* __restrict__ out,
                                   int Kout, int Kreal, int Nreal)
{
    __shared__ float tile[32][33];
    const int kb = blockIdx.x << 5;
    const int nb = blockIdx.y << 5;
    const int tx = threadIdx.x, ty = threadIdx.y;   // 32 x 8
    const int n = nb + tx;
    const float* w = (n < 200) ? w0 : (n < 400) ? w1 : w2;
    const int c = (n < 200) ? n : (n < 400) ? n - 200 : n - 400;
#pragma unroll
    for (int i = 0; i < 4; ++i) {
        const int k = kb + ty + (i << 3);
        float v = 0.f;
        if (n < Nreal && k < Kreal) v = w[(size_t)k * 200 + c];
        tile[ty + (i << 3)][tx] = v;
    }
    __syncthreads();
#pragma unroll
    for (int i = 0; i < 4; ++i) {
        const int nn = nb + ty + (i << 3);
        out[(size_t)nn * Kout + kb + tx] = f2b(tile[tx][ty + (i << 3)]);
    }
}

// ---------------- MFMA GEMM ----------------
// C[8192, ldc] = A[8192, K](bf16) @ BT[ldc, K](bf16)^T.  K % 64 == 0, ldc % 128 == 0.
// 128x128 tile, 4 waves in 2x2, each wave 4x4 of 16x16x32 MFMA, BK=64.
__global__ __launch_bounds__(256) void gemm_mfma(
    const unsigned short* __restrict__ A,
    const unsigned short* __restrict__ BT,
    float* __restrict__ C, int K, int ldc)
{
    __shared__ unsigned short As[128 * 64];
    __shared__ unsigned short Bs[128 * 64];
    const int tid  = threadIdx.x;
    const int lane = tid & 63;
    const int w    = tid >> 6;
    const int row0 = blockIdx.y << 7;
    const int col0 = blockIdx.x << 7;
    const int wm = (w >> 1) << 6;
    const int wn = (w & 1) << 6;

    // staging: thread loads 8 bf16 (16B) of row (tid>>3)+32*it, global chunk tid&7,
    // stores to LDS slot (tid&7)^(row&7)  -> conflict-free ds_read later
    const int sRow  = tid >> 3;                    // 0..31
    const int sSlot = (tid & 7) ^ (sRow & 7);
    const unsigned short* aG = A  + (size_t)(row0 + sRow) * K + ((tid & 7) << 3);
    const unsigned short* bG = BT + (size_t)(col0 + sRow) * K + ((tid & 7) << 3);
    unsigned short* aL = As + (sRow << 6) + (sSlot << 3);
    unsigned short* bL = Bs + (sRow << 6) + (sSlot << 3);

    const f32x4 zero = {0.f, 0.f, 0.f, 0.f};
    f32x4 acc[4][4];
#pragma unroll
    for (int i = 0; i < 4; ++i)
#pragma unroll
        for (int j = 0; j < 4; ++j) acc[i][j] = zero;

    s16x8 av[4], bv[4];
#pragma unroll
    for (int it = 0; it < 4; ++it) {            // prefetch k0 = 0
        av[it] = *(const s16x8*)(aG + (size_t)(it * 32) * K);
        bv[it] = *(const s16x8*)(bG + (size_t)(it * 32) * K);
    }

    for (int k0 = 0; k0 < K; k0 += 64) {
        __syncthreads();                         // previous compute done
#pragma unroll
        for (int it = 0; it < 4; ++it) {
            *(s16x8*)(aL + (it << 11)) = av[it];
            *(s16x8*)(bL + (it << 11)) = bv[it];
        }
        __syncthreads();                         // LDS tile ready
        if (k0 + 64 < K) {
#pragma unroll
            for (int it = 0; it < 4; ++it) {     // prefetch next K-step
                av[it] = *(const s16x8*)(aG + (size_t)(it * 32) * K + k0 + 64);
                bv[it] = *(const s16x8*)(bG + (size_t)(it * 32) * K + k0 + 64);
            }
        }
#pragma unroll
        for (int kk = 0; kk < 2; ++kk) {
            const int q  = (kk << 2) + (lane >> 4);      // k-chunk 0..7
            const int sl = (q ^ (lane & 7)) << 3;        // swizzled elem offset
            s16x8 af[4], bfv[4];
#pragma unroll
            for (int i = 0; i < 4; ++i) {
                const int rm = wm + (i << 4) + (lane & 15);
                af[i]  = *(const s16x8*)(As + (rm << 6) + sl);
                const int rn = wn + (i << 4) + (lane & 15);
                bfv[i] = *(const s16x8*)(Bs + (rn << 6) + sl);
            }
#pragma unroll
            for (int i = 0; i < 4; ++i)
#pragma unroll
                for (int j = 0; j < 4; ++j)
                    acc[i][j] = __builtin_amdgcn_mfma_f32_16x16x32_bf16(
                        af[i], bfv[j], acc[i][j], 0, 0, 0);
        }
    }

    const int cr = (lane >> 4) << 2;     // C/D: row = quad*4 + r, col = lane&15
    const int cc = lane & 15;
#pragma unroll
    for (int i = 0; i < 4; ++i)
#pragma unroll
        for (int j = 0; j < 4; ++j)
#pragma unroll
            for (int r = 0; r < 4; ++r)
                C[(size_t)(row0 + wm + (i << 4) + cr + r) * ldc
                  + (col0 + wn + (j << 4) + cc)] = acc[i][j][r];
}

// ---------------- edge sort (counting sort by dst) ----------------

__global__ void hist_kernel(const int* __restrict__ edges, int* __restrict__ deg)
{
    int e = blockIdx.x * 256 + threadIdx.x;
    if (e < EE) atomicAdd(&deg[edges[EE + e]], 1);
}

__global__ void scan_kernel(const int* __restrict__ deg,
                            int* __restrict__ off, int* __restrict__ pos)
{
    __shared__ int part[256];
    const int t = threadIdx.x;
    const int base = t * 32;
    int s = 0;
#pragma unroll
    for (int i = 0; i < 32; ++i) s += deg[base + i];
    part[t] = s;
    __syncthreads();
    for (int d = 1; d < 256; d <<= 1) {
        int v = (t >= d) ? part[t - d] : 0;
        __syncthreads();
        part[t] += v;
        __syncthreads();
    }
    int run = (t == 0) ? 0 : part[t - 1];
    for (int i = 0; i < 32; ++i) {
        off[base + i] = run;
        pos[base + i] = run;
        run += deg[base + i];
    }
    if (t == 255) off[NN] = run;
}

__global__ void reorder_kernel(const int* __restrict__ edges,
                               int* __restrict__ pos, int* __restrict__ sorted_src)
{
    int e = blockIdx.x * 256 + threadIdx.x;
    if (e >= EE) return;
    int p = atomicAdd(&pos[edges[EE + e]], 1);
    sorted_src[p] = edges[e];
}

// ---------------- fused aggregation: h = self + b + sum_sim + sum_rat (+relu) ----
__global__ __launch_bounds__(256) void aggregate_kernel(
    const float* __restrict__ y, const float* __restrict__ bias,
    const int* __restrict__ off_sim, const int* __restrict__ src_sim,
    const int* __restrict__ off_rat, const int* __restrict__ src_rat,
    float* __restrict__ h, int relu)
{
    const int n = blockIdx.x;
    const int j = threadIdx.x;
    if (j >= 200) return;
    float acc = y[(size_t)n * NP + j] + bias[j];
    const int s1 = off_sim[n + 1];
    for (int i = off_sim[n]; i < s1; ++i)
        acc += y[(size_t)src_sim[i] * NP + 200 + j];
    const int r1 = off_rat[n + 1];
    for (int i = off_rat[n]; i < r1; ++i)
        acc += y[(size_t)src_rat[i] * NP + 400 + j];
    if (relu) acc = fmaxf(acc, 0.f);
    h[(size_t)n * 200 + j] = acc;
}

// ---------------- decoder ----------------
__global__ void pred_kernel(const float* __restrict__ hQ,   // [8192, HPAD]
                            const float* __restrict__ h2,   // [8192, 200]
                            const int* __restrict__ edge_rat,
                            const int* __restrict__ mask,
                            float* __restrict__ out)
{
    int gid  = blockIdx.x * blockDim.x + threadIdx.x;
    int e    = gid >> 6;
    int lane = gid & 63;
    if (e >= EE) return;
    int src = edge_rat[e];
    int dst = edge_rat[EE + e];
    const float* a = hQ + (size_t)src * HPAD;
    const float* b = h2 + (size_t)dst * 200;
    float s = 0.f;
    for (int j = lane; j < 200; j += 64) s = fmaf(a[j], b[j], s);
#pragma unroll
    for (int off = 32; off > 0; off >>= 1) s += __shfl_down(s, off, 64);
    if (lane == 0) out[e] = mask[e] ? (s + 3.5f) : 0.f;
}

// ---------------- launch ----------------
extern "C" void kernel_launch(void* const* d_in, const int* in_sizes, int n_in,
                              void* d_out, int out_size, void* d_ws, size_t ws_size,
                              hipStream_t stream)
{
    const float* x       = (const float*)d_in[0];
    const int*   e_sim   = (const int*)d_in[1];
    const int*   e_rat   = (const int*)d_in[2];
    const int*   mask    = (const int*)d_in[3];
    const float* w1_self = (const float*)d_in[4];
    const float* w1_sim  = (const float*)d_in[5];
    const float* w1_rat  = (const float*)d_in[6];
    const float* b1      = (const float*)d_in[7];
    const float* w2_self = (const float*)d_in[8];
    const float* w2_sim  = (const float*)d_in[9];
    const float* w2_rat  = (const float*)d_in[10];
    const float* b2      = (const float*)d_in[11];
    const float* Q       = (const float*)d_in[12];
    float* out = (float*)d_out;

    char* p = (char*)d_ws;
    auto alloc = [&](size_t bytes) -> char* {
        char* r = p;
        p += (bytes + 255) & ~(size_t)255;
        return r;
    };
    unsigned short* xb    = (unsigned short*)alloc((size_t)NN * NN * 2);   // 134 MB
    unsigned short* wbT1  = (unsigned short*)alloc((size_t)NP * NN * 2);   // 10.5 MB
    unsigned short* wbT2  = (unsigned short*)alloc((size_t)NP * HPAD * 2);
    unsigned short* QT    = (unsigned short*)alloc((size_t)HPAD * HPAD * 2);
    float* y   = (float*)alloc((size_t)NN * NP * 4);                       // 21 MB
    float* h1  = (float*)alloc((size_t)NN * 200 * 4);
    float* h2  = (float*)alloc((size_t)NN * 200 * 4);
    unsigned short* h1b = (unsigned short*)alloc((size_t)NN * HPAD * 2);
    unsigned short* h2b = (unsigned short*)alloc((size_t)NN * HPAD * 2);
    float* hQ  = (float*)alloc((size_t)NN * HPAD * 4);                     // 8.4 MB
    int* deg_sim = (int*)alloc(NN * 4);
    int* deg_rat = (int*)alloc(NN * 4);
    int* off_sim = (int*)alloc((NN + 1) * 4);
    int* off_rat = (int*)alloc((NN + 1) * 4);
    int* pos_sim = (int*)alloc(NN * 4);
    int* pos_rat = (int*)alloc(NN * 4);
    int* srt_sim = (int*)alloc((size_t)EE * 4);
    int* srt_rat = (int*)alloc((size_t)EE * 4);

    const dim3 blk(256);
    const dim3 tblk(32, 8);

    // conversions
    cvt_x_kernel<<<(NN * (size_t)NN) / 4 / 256, blk, 0, stream>>>(x, xb);
    transpose_w_kernel<<<dim3(NN / 32, NP / 32), tblk, 0, stream>>>(
        w1_self, w1_sim, w1_rat, wbT1, NN, NN, 600);
    transpose_w_kernel<<<dim3(HPAD / 32, NP / 32), tblk, 0, stream>>>(
        w2_self, w2_sim, w2_rat, wbT2, HPAD, 200, 600);
    transpose_w_kernel<<<dim3(HPAD / 32, HPAD / 32), tblk, 0, stream>>>(
        Q, Q, Q, QT, HPAD, 200, 200);

    // edge sorts (shared by both layers)
    hipMemsetAsync(deg_sim, 0, 2 * NN * 4, stream);   // deg_sim+deg_rat contiguous
    hist_kernel<<<EE / 256, blk, 0, stream>>>(e_sim, deg_sim);
    hist_kernel<<<EE / 256, blk, 0, stream>>>(e_rat, deg_rat);
    scan_kernel<<<1, blk, 0, stream>>>(deg_sim, off_sim, pos_sim);
    scan_kernel<<<1, blk, 0, stream>>>(deg_rat, off_rat, pos_rat);
    reorder_kernel<<<EE / 256, blk, 0, stream>>>(e_sim, pos_sim, srt_sim);
    reorder_kernel<<<EE / 256, blk, 0, stream>>>(e_rat, pos_rat, srt_rat);

    // layer 1
    gemm_mfma<<<dim3(NP / 128, NN / 128), blk, 0, stream>>>(xb, wbT1, y, NN, NP);
    aggregate_kernel<<<NN, blk, 0, stream>>>(y, b1, off_sim, srt_sim,
                                             off_rat, srt_rat, h1, 1);
    cvt_h_kernel<<<NN * 64 / 256, blk, 0, stream>>>(h1, h1b);

    // layer 2
    gemm_mfma<<<dim3(NP / 128, NN / 128), blk, 0, stream>>>(h1b, wbT2, y, HPAD, NP);
    aggregate_kernel<<<NN, blk, 0, stream>>>(y, b2, off_sim, srt_sim,
                                             off_rat, srt_rat, h2, 0);
    cvt_h_kernel<<<NN * 64 / 256, blk, 0, stream>>>(h2, h2b);

    // decoder
    gemm_mfma<<<dim3(HPAD / 128, NN / 128), blk, 0, stream>>>(h2b, QT, hQ, HPAD, HPAD);
    pred_kernel<<<(EE * 64) / 256, blk, 0, stream>>>(hQ, h2, e_rat, mask, out);
}

// Round 3
// 1013.226 us; speedup vs baseline: 3.3906x; 1.2276x over previous
//
#include <hip/hip_runtime.h>

#define NN 8192
#define EE 524288
#define HPAD 256   // hidden 200 padded to 256
#define NP 640     // 3*200 output cols padded to 640 (5 x 128 tiles)

using s16x8 = __attribute__((ext_vector_type(8))) short;
using f32x4 = __attribute__((ext_vector_type(4))) float;

__device__ __forceinline__ unsigned short f2b(float f) {
    unsigned u = __float_as_uint(f);
    u = (u + 0x7FFFu + ((u >> 16) & 1u)) >> 16;   // round-to-nearest-even
    return (unsigned short)u;
}
__device__ __forceinline__ float b2f(unsigned short u) {
    return __uint_as_float((unsigned)u << 16);
}

// ---------------- conversions ----------------

// generic f32 -> bf16, n4 float4-chunks
__global__ void cvt_f2b_kernel(const float* __restrict__ in,
                               unsigned short* __restrict__ out, int n4)
{
    int i = blockIdx.x * 256 + threadIdx.x;
    if (i >= n4) return;
    float4 v = ((const float4*)in)[i];
    ushort4 o;
    o.x = f2b(v.x); o.y = f2b(v.y); o.z = f2b(v.z); o.w = f2b(v.w);
    ((ushort4*)out)[i] = o;
}

// h [8192,200] f32 -> hb [8192,HPAD] bf16, zero-padded cols 200..255
__global__ void cvt_h_kernel(const float* __restrict__ h,
                             unsigned short* __restrict__ hb)
{
    int i = blockIdx.x * 256 + threadIdx.x;      // i in [0, 8192*64)
    int n = i >> 6, j4 = (i & 63) << 2;
    ushort4 o = {0, 0, 0, 0};
    if (j4 < 200) {
        const float* p = h + (size_t)n * 200 + j4;
        o.x = f2b(p[0]); o.y = f2b(p[1]); o.z = f2b(p[2]); o.w = f2b(p[3]);
    }
    ((ushort4*)hb)[i] = o;
}

// out[n][k] (bf16, [Nout=grid.y*32, Kout]) = concat(w0|w1|w2)[k][n], zero-padded.
__global__ void transpose_w_kernel(const float* __restrict__ w0,
                                   const float* __restrict__ w1,
                                   const float* __restrict__ w2,
                                   unsigned short* __restrict__ out,
                                   int Kout, int Kreal, int Nreal)
{
    __shared__ float tile[32][33];
    const int kb = blockIdx.x << 5;
    const int nb = blockIdx.y << 5;
    const int tx = threadIdx.x, ty = threadIdx.y;   // 32 x 8
    const int n = nb + tx;
    const float* w = (n < 200) ? w0 : (n < 400) ? w1 : w2;
    const int c = (n < 200) ? n : (n < 400) ? n - 200 : n - 400;
#pragma unroll
    for (int i = 0; i < 4; ++i) {
        const int k = kb + ty + (i << 3);
        float v = 0.f;
        if (n < Nreal && k < Kreal) v = w[(size_t)k * 200 + c];
        tile[ty + (i << 3)][tx] = v;
    }
    __syncthreads();
#pragma unroll
    for (int i = 0; i < 4; ++i) {
        const int nn = nb + ty + (i << 3);
        out[(size_t)nn * Kout + kb + tx] = f2b(tile[tx][ty + (i << 3)]);
    }
}

// ---------------- MFMA GEMM (optionally split-K via blockIdx.z) ----------------
// C_plane[z][8192, ldc] = A[:, z*KC:(z+1)*KC] @ BT[:, z*KC:(z+1)*KC]^T
// A row stride = lda, BT row stride = lda.  KC % 64 == 0, ldc % 128 == 0.
__global__ __launch_bounds__(256) void gemm_mfma(
    const unsigned short* __restrict__ A,
    const unsigned short* __restrict__ BT,
    float* __restrict__ C, int lda, int KC, int ldc, size_t planeStride)
{
    __shared__ unsigned short As[128 * 64];
    __shared__ unsigned short Bs[128 * 64];
    const int tid  = threadIdx.x;
    const int lane = tid & 63;
    const int w    = tid >> 6;
    const int row0 = blockIdx.y << 7;
    const int col0 = blockIdx.x << 7;
    const int z    = blockIdx.z;
    const int wm = (w >> 1) << 6;
    const int wn = (w & 1) << 6;

    const int sRow  = tid >> 3;                    // 0..31
    const int sSlot = (tid & 7) ^ (sRow & 7);
    const unsigned short* aG = A  + (size_t)(row0 + sRow) * lda
                                  + (size_t)z * KC + ((tid & 7) << 3);
    const unsigned short* bG = BT + (size_t)(col0 + sRow) * lda
                                  + (size_t)z * KC + ((tid & 7) << 3);
    unsigned short* aL = As + (sRow << 6) + (sSlot << 3);
    unsigned short* bL = Bs + (sRow << 6) + (sSlot << 3);

    const f32x4 zero = {0.f, 0.f, 0.f, 0.f};
    f32x4 acc[4][4];
#pragma unroll
    for (int i = 0; i < 4; ++i)
#pragma unroll
        for (int j = 0; j < 4; ++j) acc[i][j] = zero;

    s16x8 av[4], bv[4];
#pragma unroll
    for (int it = 0; it < 4; ++it) {
        av[it] = *(const s16x8*)(aG + (size_t)(it * 32) * lda);
        bv[it] = *(const s16x8*)(bG + (size_t)(it * 32) * lda);
    }

    for (int k0 = 0; k0 < KC; k0 += 64) {
        __syncthreads();
#pragma unroll
        for (int it = 0; it < 4; ++it) {
            *(s16x8*)(aL + (it << 11)) = av[it];
            *(s16x8*)(bL + (it << 11)) = bv[it];
        }
        __syncthreads();
        if (k0 + 64 < KC) {
#pragma unroll
            for (int it = 0; it < 4; ++it) {
                av[it] = *(const s16x8*)(aG + (size_t)(it * 32) * lda + k0 + 64);
                bv[it] = *(const s16x8*)(bG + (size_t)(it * 32) * lda + k0 + 64);
            }
        }
#pragma unroll
        for (int kk = 0; kk < 2; ++kk) {
            const int q  = (kk << 2) + (lane >> 4);
            const int sl = (q ^ (lane & 7)) << 3;
            s16x8 af[4], bfv[4];
#pragma unroll
            for (int i = 0; i < 4; ++i) {
                const int rm = wm + (i << 4) + (lane & 15);
                af[i]  = *(const s16x8*)(As + (rm << 6) + sl);
                const int rn = wn + (i << 4) + (lane & 15);
                bfv[i] = *(const s16x8*)(Bs + (rn << 6) + sl);
            }
#pragma unroll
            for (int i = 0; i < 4; ++i)
#pragma unroll
                for (int j = 0; j < 4; ++j)
                    acc[i][j] = __builtin_amdgcn_mfma_f32_16x16x32_bf16(
                        af[i], bfv[j], acc[i][j], 0, 0, 0);
        }
    }

    float* Cp = C + (size_t)z * planeStride;
    const int cr = (lane >> 4) << 2;
    const int cc = lane & 15;
#pragma unroll
    for (int i = 0; i < 4; ++i)
#pragma unroll
        for (int j = 0; j < 4; ++j)
#pragma unroll
            for (int r = 0; r < 4; ++r)
                Cp[(size_t)(row0 + wm + (i << 4) + cr + r) * ldc
                   + (col0 + wn + (j << 4) + cc)] = acc[i][j][r];
}

// ---------------- combine split-K planes, emit fp32 self + bf16 messages ------
// p0/p1: [8192, 640] fp32 (p1 may be null). y_self: [8192,200] fp32.
// y_sr: [8192,512] bf16 — sim msg at cols 0..199, rat msg at 256..455.
__global__ void combine_kernel(const float* __restrict__ p0,
                               const float* __restrict__ p1,
                               float* __restrict__ y_self,
                               unsigned short* __restrict__ y_sr)
{
    int t = blockIdx.x * 256 + threadIdx.x;    // n*50 + j4chunk
    int n = t / 50, j4 = (t - n * 50) << 2;
    const float* a = p0 + (size_t)n * NP;
    float4 s = *(const float4*)(a + j4);
    float4 m = *(const float4*)(a + 200 + j4);
    float4 r = *(const float4*)(a + 400 + j4);
    if (p1) {
        const float* b = p1 + (size_t)n * NP;
        float4 s2 = *(const float4*)(b + j4);
        float4 m2 = *(const float4*)(b + 200 + j4);
        float4 r2 = *(const float4*)(b + 400 + j4);
        s.x += s2.x; s.y += s2.y; s.z += s2.z; s.w += s2.w;
        m.x += m2.x; m.y += m2.y; m.z += m2.z; m.w += m2.w;
        r.x += r2.x; r.y += r2.y; r.z += r2.z; r.w += r2.w;
    }
    *(float4*)(y_self + (size_t)n * 200 + j4) = s;
    ushort4 mo, ro;
    mo.x = f2b(m.x); mo.y = f2b(m.y); mo.z = f2b(m.z); mo.w = f2b(m.w);
    ro.x = f2b(r.x); ro.y = f2b(r.y); ro.z = f2b(r.z); ro.w = f2b(r.w);
    *(ushort4*)(y_sr + ((size_t)n << 9) + j4) = mo;
    *(ushort4*)(y_sr + ((size_t)n << 9) + 256 + j4) = ro;
}

// ---------------- edge sort (counting sort by dst) ----------------

__global__ void hist_kernel(const int* __restrict__ edges, int* __restrict__ deg)
{
    int e = blockIdx.x * 256 + threadIdx.x;
    if (e < EE) atomicAdd(&deg[edges[EE + e]], 1);
}

__global__ void scan_kernel(const int* __restrict__ deg,
                            int* __restrict__ off, int* __restrict__ pos)
{
    __shared__ int part[256];
    const int t = threadIdx.x;
    const int base = t * 32;
    int s = 0;
#pragma unroll
    for (int i = 0; i < 32; ++i) s += deg[base + i];
    part[t] = s;
    __syncthreads();
    for (int d = 1; d < 256; d <<= 1) {
        int v = (t >= d) ? part[t - d] : 0;
        __syncthreads();
        part[t] += v;
        __syncthreads();
    }
    int run = (t == 0) ? 0 : part[t - 1];
    for (int i = 0; i < 32; ++i) {
        off[base + i] = run;
        pos[base + i] = run;
        run += deg[base + i];
    }
    if (t == 255) off[NN] = run;
}

__global__ void reorder_kernel(const int* __restrict__ edges,
                               int* __restrict__ pos, int* __restrict__ sorted_src)
{
    int e = blockIdx.x * 256 + threadIdx.x;
    if (e >= EE) return;
    int p = atomicAdd(&pos[edges[EE + e]], 1);
    sorted_src[p] = edges[e];
}

// ---------------- fused aggregation ----------------
// One block per node. Wave w takes edges [off+w :: 4]; lane j<50 holds float4 of
// cols 4j..4j+3; partials merged via LDS; adds self+bias (+relu).
__global__ __launch_bounds__(256) void aggregate_kernel(
    const float* __restrict__ y_self, const unsigned short* __restrict__ y_sr,
    const float* __restrict__ bias,
    const int* __restrict__ off_sim, const int* __restrict__ src_sim,
    const int* __restrict__ off_rat, const int* __restrict__ src_rat,
    float* __restrict__ h, int relu)
{
    __shared__ float part[4][200];
    const int n = blockIdx.x;
    const int w = threadIdx.x >> 6;
    const int lane = threadIdx.x & 63;
    const int j4 = lane << 2;
    const bool act = lane < 50;

    float4 acc = {0.f, 0.f, 0.f, 0.f};
    const int s1 = off_sim[n + 1];
    for (int i = off_sim[n] + w; i < s1; i += 4) {
        const int src = src_sim[i];
        if (act) {
            ushort4 v = *(const ushort4*)(y_sr + ((size_t)src << 9) + j4);
            acc.x += b2f(v.x); acc.y += b2f(v.y);
            acc.z += b2f(v.z); acc.w += b2f(v.w);
        }
    }
    const int r1 = off_rat[n + 1];
    for (int i = off_rat[n] + w; i < r1; i += 4) {
        const int src = src_rat[i];
        if (act) {
            ushort4 v = *(const ushort4*)(y_sr + ((size_t)src << 9) + 256 + j4);
            acc.x += b2f(v.x); acc.y += b2f(v.y);
            acc.z += b2f(v.z); acc.w += b2f(v.w);
        }
    }
    if (act) *(float4*)&part[w][j4] = acc;
    __syncthreads();
    const int j = threadIdx.x;
    if (j < 200) {
        float v = y_self[(size_t)n * 200 + j] + bias[j]
                + part[0][j] + part[1][j] + part[2][j] + part[3][j];
        if (relu) v = fmaxf(v, 0.f);
        h[(size_t)n * 200 + j] = v;
    }
}

// ---------------- decoder ----------------
// one wave per edge; lanes 0..49 read ushort4 of both bf16 rows
__global__ void pred_kernel(const unsigned short* __restrict__ hQb, // [8192,256]
                            const unsigned short* __restrict__ h2b, // [8192,256]
                            const int* __restrict__ edge_rat,
                            const int* __restrict__ mask,
                            float* __restrict__ out)
{
    int gid  = blockIdx.x * 256 + threadIdx.x;
    int e    = gid >> 6;
    int lane = gid & 63;
    int src = edge_rat[e];
    int dst = edge_rat[EE + e];
    float s = 0.f;
    if (lane < 50) {
        ushort4 a = *(const ushort4*)(hQb + ((size_t)src << 8) + (lane << 2));
        ushort4 b = *(const ushort4*)(h2b + ((size_t)dst << 8) + (lane << 2));
        s = fmaf(b2f(a.x), b2f(b.x),
            fmaf(b2f(a.y), b2f(b.y),
            fmaf(b2f(a.z), b2f(b.z), b2f(a.w) * b2f(b.w))));
    }
#pragma unroll
    for (int off = 32; off > 0; off >>= 1) s += __shfl_down(s, off, 64);
    if (lane == 0) out[e] = mask[e] ? (s + 3.5f) : 0.f;
}

// ---------------- launch ----------------
extern "C" void kernel_launch(void* const* d_in, const int* in_sizes, int n_in,
                              void* d_out, int out_size, void* d_ws, size_t ws_size,
                              hipStream_t stream)
{
    const float* x       = (const float*)d_in[0];
    const int*   e_sim   = (const int*)d_in[1];
    const int*   e_rat   = (const int*)d_in[2];
    const int*   mask    = (const int*)d_in[3];
    const float* w1_self = (const float*)d_in[4];
    const float* w1_sim  = (const float*)d_in[5];
    const float* w1_rat  = (const float*)d_in[6];
    const float* b1      = (const float*)d_in[7];
    const float* w2_self = (const float*)d_in[8];
    const float* w2_sim  = (const float*)d_in[9];
    const float* w2_rat  = (const float*)d_in[10];
    const float* b2      = (const float*)d_in[11];
    const float* Q       = (const float*)d_in[12];
    float* out = (float*)d_out;

    char* p = (char*)d_ws;
    auto alloc = [&](size_t bytes) -> char* {
        char* r = p;
        p += (bytes + 255) & ~(size_t)255;
        return r;
    };
    unsigned short* xb    = (unsigned short*)alloc((size_t)NN * NN * 2);   // 134 MB
    unsigned short* wbT1  = (unsigned short*)alloc((size_t)NP * NN * 2);   // 10.5 MB
    unsigned short* wbT2  = (unsigned short*)alloc((size_t)NP * HPAD * 2);
    unsigned short* QT    = (unsigned short*)alloc((size_t)HPAD * HPAD * 2);
    float* ypart = (float*)alloc((size_t)2 * NN * NP * 4);                 // 42 MB
    float* y_self = (float*)alloc((size_t)NN * 200 * 4);                   // 6.6 MB
    unsigned short* y_sr = (unsigned short*)alloc((size_t)NN * 512 * 2);   // 8.4 MB
    float* h1  = (float*)alloc((size_t)NN * 200 * 4);
    float* h2  = (float*)alloc((size_t)NN * 200 * 4);
    unsigned short* h1b = (unsigned short*)alloc((size_t)NN * HPAD * 2);
    unsigned short* h2b = (unsigned short*)alloc((size_t)NN * HPAD * 2);
    unsigned short* hQb = (unsigned short*)alloc((size_t)NN * HPAD * 2);
    int* deg_sim = (int*)alloc(NN * 4);
    int* deg_rat = (int*)alloc(NN * 4);
    int* off_sim = (int*)alloc((NN + 1) * 4);
    int* off_rat = (int*)alloc((NN + 1) * 4);
    int* pos_sim = (int*)alloc(NN * 4);
    int* pos_rat = (int*)alloc(NN * 4);
    int* srt_sim = (int*)alloc((size_t)EE * 4);
    int* srt_rat = (int*)alloc((size_t)EE * 4);
    float* hQ = ypart + (size_t)NN * NP;   // reuse plane 1 (free at decoder time)

    const dim3 blk(256);
    const dim3 tblk(32, 8);

    // conversions
    cvt_f2b_kernel<<<(NN * NN / 4) / 256, blk, 0, stream>>>(x, xb, NN * NN / 4);
    transpose_w_kernel<<<dim3(NN / 32, NP / 32), tblk, 0, stream>>>(
        w1_self, w1_sim, w1_rat, wbT1, NN, NN, 600);
    transpose_w_kernel<<<dim3(HPAD / 32, NP / 32), tblk, 0, stream>>>(
        w2_self, w2_sim, w2_rat, wbT2, HPAD, 200, 600);
    transpose_w_kernel<<<dim3(HPAD / 32, HPAD / 32), tblk, 0, stream>>>(
        Q, Q, Q, QT, HPAD, 200, 200);

    // edge sorts
    hipMemsetAsync(deg_sim, 0, 2 * NN * 4, stream);
    hist_kernel<<<EE / 256, blk, 0, stream>>>(e_sim, deg_sim);
    hist_kernel<<<EE / 256, blk, 0, stream>>>(e_rat, deg_rat);
    scan_kernel<<<1, blk, 0, stream>>>(deg_sim, off_sim, pos_sim);
    scan_kernel<<<1, blk, 0, stream>>>(deg_rat, off_rat, pos_rat);
    reorder_kernel<<<EE / 256, blk, 0, stream>>>(e_sim, pos_sim, srt_sim);
    reorder_kernel<<<EE / 256, blk, 0, stream>>>(e_rat, pos_rat, srt_rat);

    // layer 1 (split-K = 2)
    gemm_mfma<<<dim3(NP / 128, NN / 128, 2), blk, 0, stream>>>(
        xb, wbT1, ypart, NN, NN / 2, NP, (size_t)NN * NP);
    combine_kernel<<<NN * 50 / 256, blk, 0, stream>>>(
        ypart, ypart + (size_t)NN * NP, y_self, y_sr);
    aggregate_kernel<<<NN, blk, 0, stream>>>(y_self, y_sr, b1, off_sim, srt_sim,
                                             off_rat, srt_rat, h1, 1);
    cvt_h_kernel<<<NN * 64 / 256, blk, 0, stream>>>(h1, h1b);

    // layer 2
    gemm_mfma<<<dim3(NP / 128, NN / 128, 1), blk, 0, stream>>>(
        h1b, wbT2, ypart, HPAD, HPAD, NP, 0);
    combine_kernel<<<NN * 50 / 256, blk, 0, stream>>>(
        ypart, nullptr, y_self, y_sr);
    aggregate_kernel<<<NN, blk, 0, stream>>>(y_self, y_sr, b2, off_sim, srt_sim,
                                             off_rat, srt_rat, h2, 0);
    cvt_h_kernel<<<NN * 64 / 256, blk, 0, stream>>>(h2, h2b);

    // decoder
    gemm_mfma<<<dim3(HPAD / 128, NN / 128, 1), blk, 0, stream>>>(
        h2b, QT, hQ, HPAD, HPAD, HPAD, 0);
    cvt_f2b_kernel<<<(NN * HPAD / 4) / 256, blk, 0, stream>>>(hQ, hQb, NN * HPAD / 4);
    pred_kernel<<<(EE * 64) / 256, blk, 0, stream>>>(hQb, h2b, e_rat, mask, out);
}